// Round 8
// baseline (279.203 us; speedup 1.0000x reference)
//
#include <hip/hip_runtime.h>

#define Bn 4
#define Cn 256
#define HWn 4096
#define CPn 64
#define MP 640   // CW rows padded 576 -> 640 (5 x 128)

typedef unsigned short u16;
typedef unsigned int u32;

using short8  = __attribute__((ext_vector_type(8))) short;
using floatx4 = __attribute__((ext_vector_type(4))) float;

static __device__ __forceinline__ u16 f2bf(float f) {
    union { float f; u32 u; } v; v.f = f;
    u32 r = (v.u + 0x7FFFu + ((v.u >> 16) & 1u)) >> 16;
    return (u16)r;
}

// async global -> LDS, 16 B per lane. LDS dest = wave-uniform base + lane*16.
static __device__ __forceinline__ void gld16(const u16* g, u16* l) {
    __builtin_amdgcn_global_load_lds(
        (const __attribute__((address_space(1))) u32*)g,
        (__attribute__((address_space(3))) u32*)l, 16, 0, 0);
}

// Pane: 64 lanes x 16B = 1 KB; lane l = (row l&15, k-quad l>>4).
// Fragment read = base + lane*16B: contiguous, bank-conflict-free.

// ---------------------------------------------------------------------------
// K1: compose CWp[s] (640 x 256) bf16 = stack of Wred[idx] @ Wqkv[3s+tt].
// rows [tt*192 + m3*64 + r]; rows 576..639 never read downstream (R<576 guard).
// ---------------------------------------------------------------------------
__global__ __launch_bounds__(256) void compose_red(
    const float* __restrict__ Wqkv, const float* __restrict__ Wred,
    u16* __restrict__ CWp)
{
    const int c0 = blockIdx.x * 64;
    const int y  = blockIdx.y;            // 0..26
    const int s  = y / 9, y9 = y % 9;
    const int tt = y9 / 3, m3 = y9 % 3;
    const int idx = (tt == 1) ? (3 * s + m3) : (3 * m3 + s);

    const float* A  = Wred + (size_t)idx * CPn * Cn;
    const float* Bm = Wqkv + (size_t)(3 * s + tt) * Cn * Cn;

    __shared__ float As[16][64];
    __shared__ float Bs[16][64];
    const int t = threadIdx.x;
    const int ty = t >> 4, tx = t & 15;
    float acc[4][4] = {};

    for (int k0 = 0; k0 < Cn; k0 += 16) {
        {
            const int r = t >> 2, eq = (t & 3) * 4;
            const float4 a = *(const float4*)(A + (size_t)r * Cn + k0 + eq);
            As[eq + 0][r] = a.x; As[eq + 1][r] = a.y; As[eq + 2][r] = a.z; As[eq + 3][r] = a.w;
        }
        {
            const int r = t >> 4, cq = (t & 15) * 4;
            *(float4*)(&Bs[r][cq]) = *(const float4*)(Bm + (size_t)(k0 + r) * Cn + c0 + cq);
        }
        __syncthreads();
        #pragma unroll
        for (int k = 0; k < 16; ++k) {
            const float4 a4 = *(const float4*)(&As[k][ty * 4]);
            const float4 b4 = *(const float4*)(&Bs[k][tx * 4]);
            const float a[4] = {a4.x, a4.y, a4.z, a4.w};
            const float bb[4] = {b4.x, b4.y, b4.z, b4.w};
            #pragma unroll
            for (int i = 0; i < 4; ++i)
                #pragma unroll
                for (int j = 0; j < 4; ++j)
                    acc[i][j] = fmaf(a[i], bb[j], acc[i][j]);
        }
        __syncthreads();
    }

    u16* outp = CWp + (size_t)s * MP * Cn;
    #pragma unroll
    for (int i = 0; i < 4; ++i) {
        const int row = tt * 192 + m3 * 64 + ty * 4 + i;
        unsigned long long pk =
            (unsigned long long)f2bf(acc[i][0]) |
            ((unsigned long long)f2bf(acc[i][1]) << 16) |
            ((unsigned long long)f2bf(acc[i][2]) << 32) |
            ((unsigned long long)f2bf(acc[i][3]) << 48);
        *(unsigned long long*)(outp + (size_t)row * Cn + c0 + tx * 4) = pk;
    }
}

// ---------------------------------------------------------------------------
// K2: FUSED pass1: per (s, nch): transpose+convert x (fp32 CxHW -> bf16 HWxC),
// write xT, AND run the 640x256 @ 256x128 reduction GEMM on the panes while
// they are resident in LDS.  Pools accumulate in registers; one partial store
// per block -> Psum/Pmax[s][R][nch] (nch = 128 chunks of 128 cols; b = nch>>5).
// ---------------------------------------------------------------------------
__global__ __launch_bounds__(256, 2) void pass1(
    const float* __restrict__ Tt, const float* __restrict__ Bt, const float* __restrict__ Mt,
    const u16* __restrict__ CWp,
    u16* __restrict__ xT, float* __restrict__ Psum, float* __restrict__ Pmax)
{
    const int s   = blockIdx.z;
    const int nch = blockIdx.x;            // 0..127
    const int b   = nch >> 5;
    const int hwb = (nch & 31) * 128;      // within-b col base (2 subtiles of 64)

    const float* X = (s == 0 ? Tt : (s == 1 ? Bt : Mt)) + (size_t)b * Cn * HWn;
    const u16* Ap = CWp + (size_t)s * MP * Cn;
    u16* xTb = xT + (size_t)((s * Bn + b) * HWn) * Cn;

    __shared__ u16 T[64][72];
    __shared__ __align__(16) u16 panes[32 * 512];   // 32 KB: 64 hw x 256 c

    const int t = threadIdx.x;
    const int w = t >> 6, lane = t & 63;
    const int l15 = lane & 15, q = lane >> 4;
    const int cl = t >> 2, q4 = t & 3;     // transpose-phase roles

    float rs[5][2][4] = {};
    float rm[5][2][4] = {};

    float4 v[2][4];
    {   // prologue load: ph 0 (st 0, ct 0)
        const float* src = X + (size_t)cl * HWn + hwb + q4 * 16;
        #pragma unroll
        for (int u = 0; u < 4; ++u) v[0][u] = *(const float4*)(src + u * 4);
    }

    for (int ph = 0; ph < 8; ++ph) {
        const int st = ph >> 2, ct = ph & 3;
        const int cur = ph & 1;
        __syncthreads();                               // T free / prior MFMA done
        if (ph < 7) {                                  // prefetch next phase's x
            const int st2 = (ph + 1) >> 2, ct2 = (ph + 1) & 3;
            const float* src = X + (size_t)(ct2 * 64 + cl) * HWn + hwb + st2 * 64 + q4 * 16;
            #pragma unroll
            for (int u = 0; u < 4; ++u) v[cur ^ 1][u] = *(const float4*)(src + u * 4);
        }
        // T write (c-row cl, 16 hw) from v[cur]
        #pragma unroll
        for (int u = 0; u < 4; ++u) {
            T[cl][q4 * 16 + u * 4 + 0] = f2bf(v[cur][u].x);
            T[cl][q4 * 16 + u * 4 + 1] = f2bf(v[cur][u].y);
            T[cl][q4 * 16 + u * 4 + 2] = f2bf(v[cur][u].z);
            T[cl][q4 * 16 + u * 4 + 3] = f2bf(v[cur][u].w);
        }
        __syncthreads();
        // pack: column wl -> 16B (8 consecutive c) -> global xT + LDS pane
        {
            const int wl  = t >> 2;
            const int hw0 = hwb + st * 64;
            #pragma unroll
            for (int u2 = 0; u2 < 2; ++u2) {
                const int cb = q4 * 16 + u2 * 8;       // c base within c-tile
                u32 w0 = (u32)T[cb + 0][wl] | ((u32)T[cb + 1][wl] << 16);
                u32 w1 = (u32)T[cb + 2][wl] | ((u32)T[cb + 3][wl] << 16);
                u32 w2 = (u32)T[cb + 4][wl] | ((u32)T[cb + 5][wl] << 16);
                u32 w3 = (u32)T[cb + 6][wl] | ((u32)T[cb + 7][wl] << 16);
                uint4 pk = {w0, w1, w2, w3};
                const int c = ct * 64 + cb;            // c within 256
                *(uint4*)(xTb + (size_t)(hw0 + wl) * Cn + c) = pk;
                const int p = (wl >> 4) * 8 + (c >> 5);
                const int cquad = (c >> 3) & 3;
                *(uint4*)(&panes[(p * 64 + cquad * 16 + (wl & 15)) * 8]) = pk;
            }
        }
        if (ct == 3) {
            __syncthreads();                           // panes complete
            #pragma unroll
            for (int mt = 0; mt < 5; ++mt) {
                short8 af[2][8];
                const u16* Arow = Ap + (size_t)(mt * 128 + w * 32 + l15) * Cn + q * 8;
                #pragma unroll
                for (int i = 0; i < 2; ++i)
                    #pragma unroll
                    for (int kk = 0; kk < 8; ++kk)
                        af[i][kk] = *(const short8*)(Arow + (size_t)(i * 16) * Cn + kk * 32);
                floatx4 acc[2][4] = {};
                #pragma unroll
                for (int kk = 0; kk < 8; ++kk) {
                    short8 bf[4];
                    #pragma unroll
                    for (int j = 0; j < 4; ++j)
                        bf[j] = *(const short8*)&panes[((j * 8 + kk) * 64 + lane) * 8];
                    #pragma unroll
                    for (int i = 0; i < 2; ++i)
                        #pragma unroll
                        for (int j = 0; j < 4; ++j)
                            acc[i][j] = __builtin_amdgcn_mfma_f32_16x16x32_bf16(af[i][kk], bf[j], acc[i][j], 0, 0, 0);
                }
                #pragma unroll
                for (int i = 0; i < 2; ++i)
                    #pragma unroll
                    for (int r = 0; r < 4; ++r) {
                        float sm = 0.f, mx = 0.f;
                        #pragma unroll
                        for (int j = 0; j < 4; ++j) {
                            const float vv = fmaxf(acc[i][j][r], 0.f);
                            sm += vv; mx = fmaxf(mx, vv);
                        }
                        rs[mt][i][r] += sm;
                        rm[mt][i][r] = fmaxf(rm[mt][i][r], mx);
                    }
            }
            // no barrier needed here: next phase's first __syncthreads covers
        }
    }

    // epilogue: reduce over the 16 cols (l15) in-wave, one store per row
    #pragma unroll
    for (int mt = 0; mt < 5; ++mt)
        #pragma unroll
        for (int i = 0; i < 2; ++i)
            #pragma unroll
            for (int r = 0; r < 4; ++r) {
                #pragma unroll
                for (int off = 1; off < 16; off <<= 1) {
                    rs[mt][i][r] += __shfl_xor(rs[mt][i][r], off);
                    rm[mt][i][r] = fmaxf(rm[mt][i][r], __shfl_xor(rm[mt][i][r], off));
                }
            }
    if (l15 == 0) {
        #pragma unroll
        for (int mt = 0; mt < 5; ++mt)
            #pragma unroll
            for (int i = 0; i < 2; ++i)
                #pragma unroll
                for (int r = 0; r < 4; ++r) {
                    const int R = mt * 128 + w * 32 + i * 16 + q * 4 + r;
                    const size_t o = ((size_t)s * MP + R) * 128 + nch;
                    Psum[o] = rs[mt][i][r];
                    Pmax[o] = rm[mt][i][r];
                }
    }
}

// ---------------------------------------------------------------------------
// K3: tiny attention per (idx,b): reduce 32 chunks -> f,g,h -> softmax -> vout.
// ---------------------------------------------------------------------------
__global__ __launch_bounds__(64) void attn_small(
    const float* __restrict__ Psum, const float* __restrict__ Pmax,
    float* __restrict__ vout)
{
    const int idx = blockIdx.x / Bn;
    const int bb  = blockIdx.x % Bn;
    __shared__ float ff[CPn], gg[CPn], hh[CPn];
    const int t = threadIdx.x;

    float v[3];
    #pragma unroll
    for (int tt = 0; tt < 3; ++tt) {
        const int s_ = (tt == 1) ? idx / 3 : idx % 3;
        const int m3 = (tt == 1) ? idx % 3 : idx / 3;
        const int R  = tt * 192 + m3 * 64 + t;
        const size_t base = ((size_t)s_ * MP + R) * 128 + bb * 32;
        float sm = 0.f, mx = 0.f;
        #pragma unroll
        for (int u = 0; u < 32; ++u) {
            sm += Psum[base + u];
            mx = fmaxf(mx, Pmax[base + u]);
        }
        v[tt] = sm * (1.0f / HWn) + mx;
    }
    gg[t] = v[0];
    ff[t] = v[1];
    hh[t] = v[2];
    __syncthreads();

    const float gj = gg[t];
    float mx = -1e30f;
    for (int i = 0; i < CPn; ++i) mx = fmaxf(mx, ff[i] * gj);
    float den = 0.f, num = 0.f;
    for (int i = 0; i < CPn; ++i) {
        const float e = expf(ff[i] * gj - mx);
        den += e;
        num += hh[i] * e;
    }
    vout[((size_t)idx * Bn + bb) * CPn + t] = num / den;
}

// ---------------------------------------------------------------------------
// K4: build Mm[b][m][s*256+c] bf16, coefs inline from vout.
// ---------------------------------------------------------------------------
__global__ __launch_bounds__(256) void build_M(
    const float* __restrict__ Wqkv, const float* __restrict__ Wrec,
    const float* __restrict__ vout, u16* __restrict__ Mm)
{
    const int s = blockIdx.x >> 8, m = blockIdx.x & 255;
    const int b = blockIdx.y;
    const int t = threadIdx.x;
    __shared__ float cc[2];

    if (t < CPn) {
        float d[6];
        #pragma unroll
        for (int j = 0; j < 6; ++j) {
            const int idx = (j < 3) ? (s + 3 * j) : (3 * s + (j - 3));
            d[j] = vout[((size_t)idx * Bn + b) * CPn + t] *
                   Wrec[((size_t)idx * Cn + m) * CPn + t];
        }
        #pragma unroll
        for (int off = 32; off >= 1; off >>= 1)
            #pragma unroll
            for (int j = 0; j < 6; ++j)
                d[j] += __shfl_xor(d[j], off);
        if (t == 0) {
            float cA = 0.f, cK = 0.f;
            #pragma unroll
            for (int j = 0; j < 3; ++j) {
                cA += 1.0f / (1.0f + expf(-d[j]));
                cK += 1.0f / (1.0f + expf(-d[j + 3]));
            }
            cc[0] = cA; cc[1] = cK;
        }
    }
    __syncthreads();
    const float cA = cc[0], cK = cc[1];
    const float wq = Wqkv[((size_t)(3 * s + 0) * Cn + m) * Cn + t];
    const float wk = Wqkv[((size_t)(3 * s + 1) * Cn + m) * Cn + t];
    const float wv = Wqkv[((size_t)(3 * s + 2) * Cn + m) * Cn + t];
    Mm[((size_t)(b * 256 + m)) * 768 + s * 256 + t] = f2bf(cA * (wq + wv) + cK * wk);
}

// ---------------------------------------------------------------------------
// K5: out[b] (256 x 4096) = Mm[b] (256 x 768) @ xcat[b]^T.
// Tile 128x128, BK=128, 6 iters, A+B dbuf, prefetch-after-barrier.
// ---------------------------------------------------------------------------
__global__ __launch_bounds__(256, 1) void final_mfma(
    const u16* __restrict__ xT, const u16* __restrict__ Mm,
    float* __restrict__ out)
{
    const int b  = blockIdx.y;
    const int mt = blockIdx.x >> 5, nt = blockIdx.x & 31;
    const int m0 = mt * 128, n0 = nt * 128;

    __shared__ __align__(16) u16 As[2][32 * 512];
    __shared__ __align__(16) u16 Bs[2][32 * 512];

    const int t = threadIdx.x;
    const int w = t >> 6, lane = t & 63;
    const int l15 = lane & 15, q = lane >> 4;
    const int rb = (w >> 1) * 64, cb = (w & 1) * 64;

    auto stage = [&](int it, int buf) {
        const int k0 = it * 128;
        const int s = k0 >> 8, c0 = k0 & 255;
        const u16* Asrc = Mm + (size_t)(b * 256 + m0 + l15) * 768 + k0 + q * 8;
        const u16* Bsrc = xT + ((size_t)((s * Bn + b) * HWn) + n0 + l15) * Cn + c0 + q * 8;
        #pragma unroll
        for (int pi = 0; pi < 8; ++pi) {
            const int p = w * 8 + pi;
            const size_t roff = (size_t)((p >> 2) * 16);
            gld16(Asrc + roff * 768 + (p & 3) * 32, &As[buf][p * 512]);
            gld16(Bsrc + roff * Cn + (p & 3) * 32, &Bs[buf][p * 512]);
        }
    };
    stage(0, 0);

    floatx4 acc[4][4] = {};

    for (int it = 0; it < 6; ++it) {
        __syncthreads();
        if (it + 1 < 6) stage(it + 1, (it + 1) & 1);
        const u16* as = As[it & 1];
        const u16* bs = Bs[it & 1];
        #pragma unroll
        for (int kk = 0; kk < 4; ++kk) {
            short8 af[4], bf[4];
            #pragma unroll
            for (int i = 0; i < 4; ++i)
                af[i] = *(const short8*)&as[((((w >> 1) * 4 + i) << 2) + kk) * 512 + lane * 8];
            #pragma unroll
            for (int j = 0; j < 4; ++j)
                bf[j] = *(const short8*)&bs[((((w & 1) * 4 + j) << 2) + kk) * 512 + lane * 8];
            #pragma unroll
            for (int i = 0; i < 4; ++i)
                #pragma unroll
                for (int j = 0; j < 4; ++j)
                    acc[i][j] = __builtin_amdgcn_mfma_f32_16x16x32_bf16(af[i], bf[j], acc[i][j], 0, 0, 0);
        }
    }

    #pragma unroll
    for (int i = 0; i < 4; ++i)
        #pragma unroll
        for (int j = 0; j < 4; ++j)
            #pragma unroll
            for (int r = 0; r < 4; ++r) {
                const int row = m0 + rb + i * 16 + q * 4 + r;
                const int col = n0 + cb + j * 16 + l15;
                out[((size_t)(b * 256) + row) * HWn + col] = acc[i][j][r];
            }
}

extern "C" void kernel_launch(void* const* d_in, const int* in_sizes, int n_in,
                              void* d_out, int out_size, void* d_ws, size_t ws_size,
                              hipStream_t stream)
{
    const float* Tt   = (const float*)d_in[0];
    const float* Bt   = (const float*)d_in[1];
    const float* Mt   = (const float*)d_in[2];
    const float* Wqkv = (const float*)d_in[3];
    const float* Wred = (const float*)d_in[4];
    const float* Wrec = (const float*)d_in[5];
    float* out = (float*)d_out;

    unsigned char* p = (unsigned char*)d_ws;
    u16* xT = (u16*)p;            p += (size_t)3 * Bn * HWn * Cn * 2;   // 25.2 MB
    u16* Mm = (u16*)p;            p += (size_t)Bn * 256 * 768 * 2;      // 1.57 MB
    u16* CWp = (u16*)p;           p += (size_t)3 * MP * Cn * 2;         // 983 KB
    float* Psum = (float*)p;      p += (size_t)3 * MP * 128 * 4;        // 983 KB
    float* Pmax = (float*)p;      p += (size_t)3 * MP * 128 * 4;        // 983 KB
    float* vout = (float*)p;      p += (size_t)9 * Bn * CPn * 4;        // 9.2 KB

    compose_red<<<dim3(4, 27),     256, 0, stream>>>(Wqkv, Wred, CWp);
    pass1      <<<dim3(128, 1, 3), 256, 0, stream>>>(Tt, Bt, Mt, CWp, xT, Psum, Pmax);
    attn_small <<<9 * Bn,           64, 0, stream>>>(Psum, Pmax, vout);
    build_M    <<<dim3(768, Bn),   256, 0, stream>>>(Wqkv, Wrec, vout, Mm);
    final_mfma <<<dim3(64, Bn),    256, 0, stream>>>(xT, Mm, out);
}